// Round 3
// baseline (9149.582 us; speedup 1.0000x reference)
//
#include <hip/hip_runtime.h>
#include <hip/hip_bf16.h>
#include <math.h>

#define DEV __device__ __forceinline__

typedef __bf16 bf16x8 __attribute__((ext_vector_type(8)));
typedef float f32x4 __attribute__((ext_vector_type(4)));
typedef unsigned short u16x8 __attribute__((ext_vector_type(8)));
typedef unsigned short u16x4 __attribute__((ext_vector_type(4)));

DEV float b2f(unsigned short u){ unsigned int i = ((unsigned int)u)<<16; float f; __builtin_memcpy(&f,&i,4); return f; }
DEV unsigned short f2b(float x){ unsigned int i; __builtin_memcpy(&i,&x,4); unsigned int r = i + 0x7FFFu + ((i>>16)&1u); return (unsigned short)(r>>16); }

enum { EPI_F32=0, EPI_BF16=1, EPI_GELU=2, EPI_RESF32=3 };

// ---------------------------------------------------------------- bf16 MFMA GEMM
// C[M,N] = A[M,K] @ Bt[N,K]^T (+bias[col]) -> bf16 out. Used only for the two
// big washout-protected GEMMs (proj_in, kv_x).
constexpr int BKG = 64;
constexpr int LDT = 72;

template<int BM, int BN, bool AF32>
__global__ __launch_bounds__(256)
void gemm_bt(const void* __restrict__ Ap, const unsigned short* __restrict__ Bt,
             const float* __restrict__ bias, unsigned short* __restrict__ Out,
             int M, int N, int K)
{
    constexpr int MR = BM/32, NR = BN/32;
    constexpr int LA = BM*BKG/(256*8);
    constexpr int LB = BN*BKG/(256*8);
    __shared__ unsigned short As[BM*LDT];
    __shared__ unsigned short Bs[BN*LDT];
    const int tid  = threadIdx.x;
    const int lane = tid & 63;
    const int wave = tid >> 6;
    const int wr = wave >> 1, wc = wave & 1;
    const int mt = blockIdx.x, nt = blockIdx.y;

    f32x4 acc[MR][NR];
    #pragma unroll
    for (int m=0;m<MR;m++)
      #pragma unroll
      for (int n=0;n<NR;n++) acc[m][n] = f32x4{0.f,0.f,0.f,0.f};

    u16x8 rA[LA]; f32x4 rAf[LA][2]; u16x8 rB[LB];

    auto issueA = [&](int k0){
      #pragma unroll
      for (int i=0;i<LA;i++){
        int e = (i*256+tid)*8; int row = e>>6, col = e&63;
        int gr = mt*BM + row; if (gr > M-1) gr = M-1;
        size_t ofs = (size_t)gr*K + (size_t)(k0+col);
        if constexpr (AF32){
          const f32x4* s = reinterpret_cast<const f32x4*>((const float*)Ap + ofs);
          rAf[i][0] = s[0]; rAf[i][1] = s[1];
        } else {
          rA[i] = *reinterpret_cast<const u16x8*>((const unsigned short*)Ap + ofs);
        }
      }
    };
    auto issueB = [&](int k0){
      #pragma unroll
      for (int i=0;i<LB;i++){
        int e = (i*256+tid)*8; int row = e>>6, col = e&63;
        size_t ofs = (size_t)(nt*BN+row)*K + (size_t)(k0+col);
        rB[i] = *reinterpret_cast<const u16x8*>(Bt + ofs);
      }
    };
    auto commit = [&](){
      #pragma unroll
      for (int i=0;i<LA;i++){
        int e = (i*256+tid)*8; int row = e>>6, col = e&63;
        u16x8 u;
        if constexpr (AF32){
          #pragma unroll
          for (int j=0;j<4;j++){ u[j] = f2b(rAf[i][0][j]); u[4+j] = f2b(rAf[i][1][j]); }
        } else u = rA[i];
        *reinterpret_cast<u16x8*>(&As[row*LDT + col]) = u;
      }
      #pragma unroll
      for (int i=0;i<LB;i++){
        int e = (i*256+tid)*8; int row = e>>6, col = e&63;
        *reinterpret_cast<u16x8*>(&Bs[row*LDT + col]) = rB[i];
      }
    };

    issueA(0); issueB(0);
    const int nk = K / BKG;
    #pragma unroll 1
    for (int kt=0; kt<nk; kt++){
      __syncthreads();
      commit();
      __syncthreads();
      if (kt+1 < nk){ issueA((kt+1)*BKG); issueB((kt+1)*BKG); }
      #pragma unroll
      for (int kk=0; kk<2; kk++){
        bf16x8 av[MR], bv[NR];
        #pragma unroll
        for (int m=0;m<MR;m++){
          int r = wr*(BM/2) + m*16 + (lane&15);
          av[m] = (bf16x8)(*reinterpret_cast<const u16x8*>(&As[r*LDT + kk*32 + (lane>>4)*8]));
        }
        #pragma unroll
        for (int n=0;n<NR;n++){
          int r = wc*(BN/2) + n*16 + (lane&15);
          bv[n] = (bf16x8)(*reinterpret_cast<const u16x8*>(&Bs[r*LDT + kk*32 + (lane>>4)*8]));
        }
        #pragma unroll
        for (int m=0;m<MR;m++)
          #pragma unroll
          for (int n=0;n<NR;n++)
            acc[m][n] = __builtin_amdgcn_mfma_f32_16x16x32_bf16(av[m], bv[n], acc[m][n], 0, 0, 0);
      }
    }

    #pragma unroll
    for (int m=0;m<MR;m++){
      #pragma unroll
      for (int n=0;n<NR;n++){
        #pragma unroll
        for (int r=0;r<4;r++){
          int row = mt*BM + wr*(BM/2) + m*16 + (lane>>4)*4 + r;
          int col = nt*BN + wc*(BN/2) + n*16 + (lane&15);
          if (row < M){
            float v = acc[m][n][r];
            if (bias) v += bias[col];
            Out[(size_t)row*N + col] = f2b(v);
          }
        }
      }
    }
}

// ---------------------------------------------------------------- fp32 VALU GEMM
// C[M,N] = A[M,K] @ B[K,N] (B in ORIGINAL row-major layout, fp32, no transpose)
// M,N,K all multiples of 64/16 in our uses. 64x64 tile, K-step 16, 4x4/thread.
template<int EPI>
__global__ __launch_bounds__(256)
void gemm_f32(const float* __restrict__ A, const float* __restrict__ B,
              const float* __restrict__ bias, const float* Res, float* Out,
              int M, int N, int K)
{
  __shared__ float As[64][17];
  __shared__ float Bs[16][68];
  const int tid = threadIdx.x;
  const int mt = blockIdx.x, nt = blockIdx.y;
  const int ty = tid >> 4, tx = tid & 15;
  float acc[4][4] = {{0.f}};

  for (int k0 = 0; k0 < K; k0 += 16){
    {
      int row = tid >> 2, kk = (tid & 3) * 4;
      f32x4 v = *reinterpret_cast<const f32x4*>(&A[(size_t)(mt*64+row)*K + k0 + kk]);
      As[row][kk+0] = v[0]; As[row][kk+1] = v[1]; As[row][kk+2] = v[2]; As[row][kk+3] = v[3];
    }
    {
      int kk = tid >> 4, n = (tid & 15) * 4;
      f32x4 v = *reinterpret_cast<const f32x4*>(&B[(size_t)(k0+kk)*N + nt*64 + n]);
      Bs[kk][n+0] = v[0]; Bs[kk][n+1] = v[1]; Bs[kk][n+2] = v[2]; Bs[kk][n+3] = v[3];
    }
    __syncthreads();
    #pragma unroll
    for (int kk=0; kk<16; kk++){
      float a0 = As[ty*4+0][kk], a1 = As[ty*4+1][kk], a2 = As[ty*4+2][kk], a3 = As[ty*4+3][kk];
      float b0 = Bs[kk][tx*4+0], b1 = Bs[kk][tx*4+1], b2 = Bs[kk][tx*4+2], b3 = Bs[kk][tx*4+3];
      acc[0][0] += a0*b0; acc[0][1] += a0*b1; acc[0][2] += a0*b2; acc[0][3] += a0*b3;
      acc[1][0] += a1*b0; acc[1][1] += a1*b1; acc[1][2] += a1*b2; acc[1][3] += a1*b3;
      acc[2][0] += a2*b0; acc[2][1] += a2*b1; acc[2][2] += a2*b2; acc[2][3] += a2*b3;
      acc[3][0] += a3*b0; acc[3][1] += a3*b1; acc[3][2] += a3*b2; acc[3][3] += a3*b3;
    }
    __syncthreads();
  }

  #pragma unroll
  for (int i=0;i<4;i++){
    int row = mt*64 + ty*4 + i;
    #pragma unroll
    for (int j=0;j<4;j++){
      int col = nt*64 + tx*4 + j;
      float v = acc[i][j];
      if (bias) v += bias[col];
      if constexpr (EPI==EPI_GELU)   v = 0.5f*v*(1.0f + erff(v*0.70710678118654752f));
      if constexpr (EPI==EPI_RESF32) v += Res[(size_t)row*N + col];
      Out[(size_t)row*N + col] = v;
    }
  }
}

// ---------------------------------------------------------------- LayerNorm (rows of 1024)
template<bool INF32, bool OUTF32, bool HASGB>
__global__ __launch_bounds__(256)
void ln_rows(const void* __restrict__ In, void* __restrict__ Out,
             const float* __restrict__ g, const float* __restrict__ bb)
{
  const int row = blockIdx.x;
  const int tid = threadIdx.x;
  const size_t base = (size_t)row*1024 + tid*4;
  float v[4];
  if constexpr (INF32){
    f32x4 t = *reinterpret_cast<const f32x4*>((const float*)In + base);
    v[0]=t[0]; v[1]=t[1]; v[2]=t[2]; v[3]=t[3];
  } else {
    u16x4 t = *reinterpret_cast<const u16x4*>((const unsigned short*)In + base);
    #pragma unroll
    for (int j=0;j<4;j++) v[j] = b2f(t[j]);
  }
  float s = v[0]+v[1]+v[2]+v[3];
  float q = v[0]*v[0]+v[1]*v[1]+v[2]*v[2]+v[3]*v[3];
  #pragma unroll
  for (int o=32;o>0;o>>=1){ s += __shfl_xor(s,o,64); q += __shfl_xor(q,o,64); }
  __shared__ float sm[8];
  const int wave = tid>>6, lane = tid&63;
  if (lane==0){ sm[wave] = s; sm[4+wave] = q; }
  __syncthreads();
  s = sm[0]+sm[1]+sm[2]+sm[3];
  q = sm[4]+sm[5]+sm[6]+sm[7];
  const float mean = s*(1.f/1024.f);
  const float rstd = rsqrtf(fmaxf(q*(1.f/1024.f) - mean*mean, 0.f) + 1e-5f);
  #pragma unroll
  for (int j=0;j<4;j++){
    float t2 = (v[j]-mean)*rstd;
    if constexpr (HASGB) t2 = t2*g[tid*4+j] + bb[tid*4+j];
    v[j] = t2;
  }
  if constexpr (OUTF32){
    f32x4 t{v[0],v[1],v[2],v[3]};
    *reinterpret_cast<f32x4*>((float*)Out + base) = t;
  } else {
    u16x4 t{f2b(v[0]),f2b(v[1]),f2b(v[2]),f2b(v[3])};
    *reinterpret_cast<u16x4*>((unsigned short*)Out + base) = t;
  }
}

// ---------------------------------------------------------------- misc
__global__ __launch_bounds__(256)
void transpose_cvt(const float* __restrict__ W, const float* __restrict__ rs,
                   unsigned short* __restrict__ Wt, int K, int N)
{
  __shared__ float t[32][33];
  const int tx = threadIdx.x & 31, ty = threadIdx.x >> 5;
  const int n0 = blockIdx.x*32, k0 = blockIdx.y*32;
  #pragma unroll
  for (int j=0;j<4;j++){
    int r = ty + j*8;
    float w = W[(size_t)(k0+r)*N + n0 + tx];
    if (rs) w *= rs[k0+r];
    t[r][tx] = w;
  }
  __syncthreads();
  #pragma unroll
  for (int j=0;j<4;j++){
    int r = ty + j*8;
    Wt[(size_t)(n0+r)*K + k0 + tx] = f2b(t[tx][r]);
  }
}

__global__ __launch_bounds__(256)
void biaskv_kernel(const float* __restrict__ ln1b, const float* __restrict__ wkv,
                   float* __restrict__ out)
{
  const int l = blockIdx.y;
  const int n = blockIdx.x*256 + threadIdx.x;
  const float* b1 = ln1b + l*1024;
  const float* W  = wkv + (size_t)l*1024*2048;
  float s = 0.f;
  for (int k=0;k<1024;k++) s += b1[k]*W[(size_t)k*2048 + n];
  out[l*2048 + n] = s;
}

__global__ __launch_bounds__(256)
void init_latents(const float* __restrict__ Q, float* __restrict__ L)
{
  size_t idx = ((size_t)blockIdx.x*256 + threadIdx.x)*4;
  int row = (int)(idx >> 10);
  int col = (int)(idx & 1023);
  f32x4 t = *reinterpret_cast<const f32x4*>(Q + (size_t)(row & 15)*1024 + col);
  *reinterpret_cast<f32x4*>(L + idx) = t;
}

// ---------------------------------------------------------------- attention
// one block per (b,h). q: fp32 from QLTf; K/V rows 0..576 bf16 from KVX,
// rows 577..592 fp32 from KVLTf (latents). Output fp32.
__global__ __launch_bounds__(256)
void attn_kernel(const float* __restrict__ QLTf,
                 const unsigned short* __restrict__ KVX,
                 const float* __restrict__ KVLTf,
                 float* __restrict__ ATTOf)
{
  __shared__ float qs[16][64];
  __shared__ float ws[16][600];
  const int tid = threadIdx.x;
  const int bh = blockIdx.x;
  const int b = bh >> 4, h = bh & 15;

  { // load q, fold logits scale s^2 = 1/8
    int idx = tid*4;
    int qi = idx >> 6, d = idx & 63;
    f32x4 t = *reinterpret_cast<const f32x4*>(QLTf + (size_t)(b*16+qi)*1024 + h*64 + d);
    #pragma unroll
    for (int j=0;j<4;j++) qs[qi][d+j] = 0.125f * t[j];
  }
  __syncthreads();

  for (int r = tid; r < 593; r += 256){
    float a[16];
    #pragma unroll
    for (int qi=0;qi<16;qi++) a[qi] = 0.f;
    if (r < 577){
      const unsigned short* krow = KVX + ((size_t)(b*577 + r)*2048 + h*64);
      #pragma unroll 4
      for (int d4=0; d4<16; d4++){
        u16x4 k4 = *reinterpret_cast<const u16x4*>(krow + d4*4);
        float kf0=b2f(k4[0]), kf1=b2f(k4[1]), kf2=b2f(k4[2]), kf3=b2f(k4[3]);
        #pragma unroll
        for (int qi=0;qi<16;qi++){
          f32x4 q4 = *reinterpret_cast<const f32x4*>(&qs[qi][d4*4]);
          a[qi] += q4[0]*kf0 + q4[1]*kf1 + q4[2]*kf2 + q4[3]*kf3;
        }
      }
    } else {
      const float* krow = KVLTf + ((size_t)(b*16 + (r-577))*2048 + h*64);
      #pragma unroll 4
      for (int d4=0; d4<16; d4++){
        f32x4 k4 = *reinterpret_cast<const f32x4*>(krow + d4*4);
        #pragma unroll
        for (int qi=0;qi<16;qi++){
          f32x4 q4 = *reinterpret_cast<const f32x4*>(&qs[qi][d4*4]);
          a[qi] += q4[0]*k4[0] + q4[1]*k4[1] + q4[2]*k4[2] + q4[3]*k4[3];
        }
      }
    }
    #pragma unroll
    for (int qi=0;qi<16;qi++) ws[qi][r] = a[qi];
  }
  __syncthreads();

  const int wave = tid>>6, lane = tid&63;
  for (int qi = wave; qi < 16; qi += 4){
    float m = -1e30f;
    for (int r = lane; r < 593; r += 64) m = fmaxf(m, ws[qi][r]);
    #pragma unroll
    for (int o=32;o>0;o>>=1) m = fmaxf(m, __shfl_xor(m,o,64));
    float s = 0.f;
    for (int r = lane; r < 593; r += 64){ float e = expf(ws[qi][r]-m); ws[qi][r] = e; s += e; }
    #pragma unroll
    for (int o=32;o>0;o>>=1) s += __shfl_xor(s,o,64);
    float inv = 1.f/s;
    for (int r = lane; r < 593; r += 64) ws[qi][r] *= inv;
  }
  __syncthreads();

  const int d = tid & 63, qg = tid >> 6;
  float o0=0.f,o1=0.f,o2=0.f,o3=0.f;
  // rows 0..575 (bf16 V from KVX)
  for (int rr=0; rr<576; rr+=4){
    f32x4 w0 = *reinterpret_cast<const f32x4*>(&ws[qg   ][rr]);
    f32x4 w1 = *reinterpret_cast<const f32x4*>(&ws[qg+4 ][rr]);
    f32x4 w2 = *reinterpret_cast<const f32x4*>(&ws[qg+8 ][rr]);
    f32x4 w3 = *reinterpret_cast<const f32x4*>(&ws[qg+12][rr]);
    #pragma unroll
    for (int j=0;j<4;j++){
      const unsigned short* vrow = KVX + ((size_t)(b*577 + rr + j)*2048 + 1024 + h*64);
      float v = b2f(vrow[d]);
      o0 += w0[j]*v; o1 += w1[j]*v; o2 += w2[j]*v; o3 += w3[j]*v;
    }
  }
  { // row 576 (last x token)
    float v = b2f(KVX[(size_t)(b*577 + 576)*2048 + 1024 + h*64 + d]);
    o0 += ws[qg][576]*v; o1 += ws[qg+4][576]*v; o2 += ws[qg+8][576]*v; o3 += ws[qg+12][576]*v;
  }
  // rows 577..592 (fp32 latent V from KVLTf)
  for (int r=577; r<593; r++){
    float v = KVLTf[(size_t)(b*16 + (r-577))*2048 + 1024 + h*64 + d];
    o0 += ws[qg][r]*v; o1 += ws[qg+4][r]*v; o2 += ws[qg+8][r]*v; o3 += ws[qg+12][r]*v;
  }
  ATTOf[(size_t)(b*16+qg   )*1024 + h*64 + d] = o0;
  ATTOf[(size_t)(b*16+qg+4 )*1024 + h*64 + d] = o1;
  ATTOf[(size_t)(b*16+qg+8 )*1024 + h*64 + d] = o2;
  ATTOf[(size_t)(b*16+qg+12)*1024 + h*64 + d] = o3;
}

// ---------------------------------------------------------------- host
extern "C" void kernel_launch(void* const* d_in, const int* in_sizes, int n_in,
                              void* d_out, int out_size, void* d_ws, size_t ws_size,
                              hipStream_t stream)
{
  const float* x    = (const float*)d_in[0];
  const float* qry  = (const float*)d_in[1];
  const float* piw  = (const float*)d_in[2];
  const float* pib  = (const float*)d_in[3];
  const float* ln1g = (const float*)d_in[4];
  const float* ln1b = (const float*)d_in[5];
  const float* ln2g = (const float*)d_in[6];
  const float* ln2b = (const float*)d_in[7];
  const float* wq   = (const float*)d_in[8];
  const float* wkv  = (const float*)d_in[9];
  const float* wo   = (const float*)d_in[10];
  const float* ffg  = (const float*)d_in[11];
  const float* ffb  = (const float*)d_in[12];
  const float* w1   = (const float*)d_in[13];
  const float* w2   = (const float*)d_in[14];
  const float* pow_ = (const float*)d_in[15];
  const float* pob  = (const float*)d_in[16];
  const float* ng   = (const float*)d_in[17];
  const float* nb   = (const float*)d_in[18];

  const int MROWS = 64*577;     // 36928
  char* wsb = (char*)d_ws;
  size_t off = 0;
  auto alloc = [&](size_t bytes)->char*{
    char* p = wsb + off; off = (off + bytes + 255) & ~(size_t)255; return p;
  };
  unsigned short* XP    = (unsigned short*)alloc((size_t)36992*1024*2);
  unsigned short* KVX   = (unsigned short*)alloc((size_t)36992*2048*2);
  unsigned short* WpiT  = (unsigned short*)alloc((size_t)1024*768*2);
  unsigned short* WkvTs = (unsigned short*)alloc((size_t)2048*1024*2);
  float*          BKV   = (float*)alloc((size_t)8*2048*4);
  float*          LTf   = (float*)alloc((size_t)1024*1024*4);
  float*          QLTf  = (float*)alloc((size_t)1024*1024*4);
  float*          KVLTf = (float*)alloc((size_t)1024*2048*4);
  float*          ATTOf = (float*)alloc((size_t)1024*1024*4);
  float*          FFINf = (float*)alloc((size_t)1024*1024*4);
  float*          FFHf  = (float*)alloc((size_t)1024*4096*4);
  float*          LATF  = (float*)alloc((size_t)1024*1024*4);
  float*          OUTP  = (float*)alloc((size_t)1024*1024*4);
  if (off > ws_size) return;  // loud failure (output stays zero)

  dim3 blk(256);

  // ---- prep
  transpose_cvt<<<dim3(32,24), blk, 0, stream>>>(piw, nullptr, WpiT, 768, 1024);
  biaskv_kernel<<<dim3(8,8),   blk, 0, stream>>>(ln1b, wkv, BKV);
  init_latents<<<dim3(1024),   blk, 0, stream>>>(qry, LATF);

  // xp = x @ proj_in_w + b  (bf16 MFMA), then LN in place -> xhat (bf16)
  gemm_bt<128,128,true><<<dim3(289,8), blk, 0, stream>>>(
      x, WpiT, pib, XP, MROWS, 1024, 768);
  ln_rows<false,false,false><<<dim3(MROWS), blk, 0, stream>>>(XP, XP, nullptr, nullptr);

  for (int l=0; l<8; l++){
    // g1-scaled Wkv^T for the big kv GEMM
    transpose_cvt<<<dim3(64,32), blk, 0, stream>>>(wkv + (size_t)l*1024*2048, ln1g + l*1024, WkvTs, 1024, 2048);

    // lt = LN(latents, g2,b2)  (fp32)
    ln_rows<true,true,true><<<dim3(1024), blk, 0, stream>>>(LATF, LTf, ln2g + l*1024, ln2b + l*1024);
    // q_lt = lt @ Wq (fp32) ; kv_lt = lt @ Wkv (fp32)
    gemm_f32<EPI_F32><<<dim3(16,16), blk, 0, stream>>>(
        LTf, wq + (size_t)l*1024*1024, nullptr, nullptr, QLTf, 1024, 1024, 1024);
    gemm_f32<EPI_F32><<<dim3(16,32), blk, 0, stream>>>(
        LTf, wkv + (size_t)l*1024*2048, nullptr, nullptr, KVLTf, 1024, 2048, 1024);
    // kv_x = xhat @ (g1-scaled Wkv) + b1@Wkv   (bf16 MFMA)
    gemm_bt<128,128,false><<<dim3(289,16), blk, 0, stream>>>(
        XP, WkvTs, BKV + l*2048, KVX, MROWS, 2048, 1024);
    // attention (fp32 softmax; fp32 q and latent k/v)
    attn_kernel<<<dim3(1024), blk, 0, stream>>>(QLTf, KVX, KVLTf, ATTOf);
    // latents += o @ Wo  (fp32)
    gemm_f32<EPI_RESF32><<<dim3(16,16), blk, 0, stream>>>(
        ATTOf, wo + (size_t)l*1024*1024, nullptr, LATF, LATF, 1024, 1024, 1024);
    // FF (fp32)
    ln_rows<true,true,true><<<dim3(1024), blk, 0, stream>>>(LATF, FFINf, ffg + l*1024, ffb + l*1024);
    gemm_f32<EPI_GELU><<<dim3(16,64), blk, 0, stream>>>(
        FFINf, w1 + (size_t)l*1024*4096, nullptr, nullptr, FFHf, 1024, 4096, 1024);
    gemm_f32<EPI_RESF32><<<dim3(16,16), blk, 0, stream>>>(
        FFHf, w2 + (size_t)l*4096*1024, nullptr, LATF, LATF, 1024, 1024, 4096);
  }

  // out = LN(latents @ Wpo + b, nout)  (fp32)
  gemm_f32<EPI_F32><<<dim3(16,16), blk, 0, stream>>>(
      LATF, pow_, pob, nullptr, OUTP, 1024, 1024, 1024);
  ln_rows<true,true,true><<<dim3(1024), blk, 0, stream>>>(OUTP, d_out, ng, nb);
}

// Round 4
// 5506.911 us; speedup vs baseline: 1.6615x; 1.6615x over previous
//
#include <hip/hip_runtime.h>
#include <hip/hip_bf16.h>
#include <math.h>

#define DEV __device__ __forceinline__

typedef __bf16 bf16x8 __attribute__((ext_vector_type(8)));
typedef float f32x4 __attribute__((ext_vector_type(4)));
typedef unsigned short u16x8 __attribute__((ext_vector_type(8)));
typedef unsigned short u16x4 __attribute__((ext_vector_type(4)));

DEV float b2f(unsigned short u){ unsigned int i = ((unsigned int)u)<<16; float f; __builtin_memcpy(&f,&i,4); return f; }
DEV unsigned short f2b(float x){ unsigned int i; __builtin_memcpy(&i,&x,4); unsigned int r = i + 0x7FFFu + ((i>>16)&1u); return (unsigned short)(r>>16); }

// XOR-swizzled element index within a [rows][64] u16 plane (16B-unit swizzle).
DEV int swz(int row, int elem){ return row*64 + ((((elem>>3) ^ row) & 7)<<3) + (elem&7); }

enum { EPI_F32=0, EPI_GELU=2, EPI_RESF32=3 };

// ---------------------------------------------------------------- bf16 MFMA GEMM (big, washout-protected)
// C[M,N] = A[M,K] @ Bt[N,K]^T (+bias[col]) -> bf16 out.  nt = blockIdx.x (fastest) for L2 reuse of A panel.
constexpr int BKG = 64;

template<int BM, int BN, bool AF32>
__global__ __launch_bounds__(256)
void gemm_bt(const void* __restrict__ Ap, const unsigned short* __restrict__ Bt,
             const float* __restrict__ bias, unsigned short* __restrict__ Out,
             int M, int N, int K)
{
    constexpr int MR = BM/32, NR = BN/32;
    constexpr int LA = BM*BKG/(256*8);
    constexpr int LB = BN*BKG/(256*8);
    __shared__ unsigned short As[BM*64];
    __shared__ unsigned short Bs[BN*64];
    const int tid  = threadIdx.x;
    const int lane = tid & 63;
    const int wave = tid >> 6;
    const int wr = wave >> 1, wc = wave & 1;
    const int nt = blockIdx.x, mt = blockIdx.y;

    f32x4 acc[MR][NR];
    #pragma unroll
    for (int m=0;m<MR;m++)
      #pragma unroll
      for (int n=0;n<NR;n++) acc[m][n] = f32x4{0.f,0.f,0.f,0.f};

    u16x8 rA[LA]; f32x4 rAf[LA][2]; u16x8 rB[LB];

    auto issueA = [&](int k0){
      #pragma unroll
      for (int i=0;i<LA;i++){
        int e = (i*256+tid)*8; int row = e>>6, col = e&63;
        int gr = mt*BM + row; if (gr > M-1) gr = M-1;
        size_t ofs = (size_t)gr*K + (size_t)(k0+col);
        if constexpr (AF32){
          const f32x4* s = reinterpret_cast<const f32x4*>((const float*)Ap + ofs);
          rAf[i][0] = s[0]; rAf[i][1] = s[1];
        } else {
          rA[i] = *reinterpret_cast<const u16x8*>((const unsigned short*)Ap + ofs);
        }
      }
    };
    auto issueB = [&](int k0){
      #pragma unroll
      for (int i=0;i<LB;i++){
        int e = (i*256+tid)*8; int row = e>>6, col = e&63;
        size_t ofs = (size_t)(nt*BN+row)*K + (size_t)(k0+col);
        rB[i] = *reinterpret_cast<const u16x8*>(Bt + ofs);
      }
    };
    auto commit = [&](){
      #pragma unroll
      for (int i=0;i<LA;i++){
        int e = (i*256+tid)*8; int row = e>>6, col = e&63;
        u16x8 u;
        if constexpr (AF32){
          #pragma unroll
          for (int j=0;j<4;j++){ u[j] = f2b(rAf[i][0][j]); u[4+j] = f2b(rAf[i][1][j]); }
        } else u = rA[i];
        *reinterpret_cast<u16x8*>(&As[swz(row,col)]) = u;
      }
      #pragma unroll
      for (int i=0;i<LB;i++){
        int e = (i*256+tid)*8; int row = e>>6, col = e&63;
        *reinterpret_cast<u16x8*>(&Bs[swz(row,col)]) = rB[i];
      }
    };

    issueA(0); issueB(0);
    const int nk = K / BKG;
    #pragma unroll 1
    for (int kt=0; kt<nk; kt++){
      __syncthreads();
      commit();
      __syncthreads();
      if (kt+1 < nk){ issueA((kt+1)*BKG); issueB((kt+1)*BKG); }
      #pragma unroll
      for (int kk=0; kk<2; kk++){
        bf16x8 av[MR], bv[NR];
        #pragma unroll
        for (int m=0;m<MR;m++){
          int r = wr*(BM/2) + m*16 + (lane&15);
          av[m] = (bf16x8)(*reinterpret_cast<const u16x8*>(&As[swz(r, kk*32 + (lane>>4)*8)]));
        }
        #pragma unroll
        for (int n=0;n<NR;n++){
          int r = wc*(BN/2) + n*16 + (lane&15);
          bv[n] = (bf16x8)(*reinterpret_cast<const u16x8*>(&Bs[swz(r, kk*32 + (lane>>4)*8)]));
        }
        #pragma unroll
        for (int m=0;m<MR;m++)
          #pragma unroll
          for (int n=0;n<NR;n++)
            acc[m][n] = __builtin_amdgcn_mfma_f32_16x16x32_bf16(av[m], bv[n], acc[m][n], 0, 0, 0);
      }
    }

    #pragma unroll
    for (int m=0;m<MR;m++){
      #pragma unroll
      for (int n=0;n<NR;n++){
        #pragma unroll
        for (int r=0;r<4;r++){
          int row = mt*BM + wr*(BM/2) + m*16 + (lane>>4)*4 + r;
          int col = nt*BN + wc*(BN/2) + n*16 + (lane&15);
          if (row < M){
            float v = acc[m][n][r];
            if (bias) v += bias[col];
            Out[(size_t)row*N + col] = f2b(v);
          }
        }
      }
    }
}

// ---------------------------------------------------------------- split (Ootomo) MFMA GEMM, fp32-accurate
// C[M,N] = A[M,K](f32) @ Bt(hi,lo)[N,K]^T (+bias) (+Res) -> f32 out.
// A split to hi/lo bf16 in-kernel; 3 MFMAs per fragment pair (AhBh + AhBl + AlBh).
template<int EPI>
__global__ __launch_bounds__(256)
void gemm_sp(const float* __restrict__ A,
             const unsigned short* __restrict__ BtH, const unsigned short* __restrict__ BtL,
             const float* __restrict__ bias, const float* __restrict__ Res,
             float* __restrict__ Out, int M, int N, int K)
{
    constexpr int BM=64, BN=64, MR=2, NR=2, LA=2, LB=2;
    __shared__ unsigned short As[2*BM*64];   // hi plane, lo plane
    __shared__ unsigned short Bs[2*BN*64];
    const int tid  = threadIdx.x;
    const int lane = tid & 63;
    const int wave = tid >> 6;
    const int wr = wave >> 1, wc = wave & 1;
    const int mt = blockIdx.x, nt = blockIdx.y;

    f32x4 acc[MR][NR];
    #pragma unroll
    for (int m=0;m<MR;m++)
      #pragma unroll
      for (int n=0;n<NR;n++) acc[m][n] = f32x4{0.f,0.f,0.f,0.f};

    f32x4 rAf[LA][2]; u16x8 rBh[LB], rBl[LB];

    auto issueA = [&](int k0){
      #pragma unroll
      for (int i=0;i<LA;i++){
        int e = (i*256+tid)*8; int row = e>>6, col = e&63;
        const f32x4* s = reinterpret_cast<const f32x4*>(&A[(size_t)(mt*BM+row)*K + k0 + col]);
        rAf[i][0] = s[0]; rAf[i][1] = s[1];
      }
    };
    auto issueB = [&](int k0){
      #pragma unroll
      for (int i=0;i<LB;i++){
        int e = (i*256+tid)*8; int row = e>>6, col = e&63;
        size_t ofs = (size_t)(nt*BN+row)*K + (size_t)(k0+col);
        rBh[i] = *reinterpret_cast<const u16x8*>(BtH + ofs);
        rBl[i] = *reinterpret_cast<const u16x8*>(BtL + ofs);
      }
    };
    auto commit = [&](){
      #pragma unroll
      for (int i=0;i<LA;i++){
        int e = (i*256+tid)*8; int row = e>>6, col = e&63;
        u16x8 h, l;
        #pragma unroll
        for (int j=0;j<4;j++){
          float v0 = rAf[i][0][j], v1 = rAf[i][1][j];
          h[j]   = f2b(v0); l[j]   = f2b(v0 - b2f(h[j]));
          h[4+j] = f2b(v1); l[4+j] = f2b(v1 - b2f(h[4+j]));
        }
        int a = swz(row,col);
        *reinterpret_cast<u16x8*>(&As[a]) = h;
        *reinterpret_cast<u16x8*>(&As[BM*64 + a]) = l;
      }
      #pragma unroll
      for (int i=0;i<LB;i++){
        int e = (i*256+tid)*8; int row = e>>6, col = e&63;
        int a = swz(row,col);
        *reinterpret_cast<u16x8*>(&Bs[a]) = rBh[i];
        *reinterpret_cast<u16x8*>(&Bs[BN*64 + a]) = rBl[i];
      }
    };

    issueA(0); issueB(0);
    const int nk = K / BKG;
    #pragma unroll 1
    for (int kt=0; kt<nk; kt++){
      __syncthreads();
      commit();
      __syncthreads();
      if (kt+1 < nk){ issueA((kt+1)*BKG); issueB((kt+1)*BKG); }
      #pragma unroll
      for (int kk=0; kk<2; kk++){
        bf16x8 ah[MR], al[MR], bh[NR], bl[NR];
        #pragma unroll
        for (int m=0;m<MR;m++){
          int a = swz(wr*32 + m*16 + (lane&15), kk*32 + (lane>>4)*8);
          ah[m] = (bf16x8)(*reinterpret_cast<const u16x8*>(&As[a]));
          al[m] = (bf16x8)(*reinterpret_cast<const u16x8*>(&As[BM*64 + a]));
        }
        #pragma unroll
        for (int n=0;n<NR;n++){
          int a = swz(wc*32 + n*16 + (lane&15), kk*32 + (lane>>4)*8);
          bh[n] = (bf16x8)(*reinterpret_cast<const u16x8*>(&Bs[a]));
          bl[n] = (bf16x8)(*reinterpret_cast<const u16x8*>(&Bs[BN*64 + a]));
        }
        #pragma unroll
        for (int m=0;m<MR;m++)
          #pragma unroll
          for (int n=0;n<NR;n++){
            acc[m][n] = __builtin_amdgcn_mfma_f32_16x16x32_bf16(ah[m], bh[n], acc[m][n], 0, 0, 0);
            acc[m][n] = __builtin_amdgcn_mfma_f32_16x16x32_bf16(ah[m], bl[n], acc[m][n], 0, 0, 0);
            acc[m][n] = __builtin_amdgcn_mfma_f32_16x16x32_bf16(al[m], bh[n], acc[m][n], 0, 0, 0);
          }
      }
    }

    #pragma unroll
    for (int m=0;m<MR;m++){
      #pragma unroll
      for (int n=0;n<NR;n++){
        #pragma unroll
        for (int r=0;r<4;r++){
          int row = mt*BM + wr*32 + m*16 + (lane>>4)*4 + r;
          int col = nt*BN + wc*32 + n*16 + (lane&15);
          float v = acc[m][n][r];
          if (bias) v += bias[col];
          if constexpr (EPI==EPI_GELU)   v = 0.5f*v*(1.0f + erff(v*0.70710678118654752f));
          if constexpr (EPI==EPI_RESF32) v += Res[(size_t)row*N + col];
          Out[(size_t)row*N + col] = v;
        }
      }
    }
}

// ---------------------------------------------------------------- LayerNorm (rows of 1024)
template<bool INF32, bool OUTF32, bool HASGB>
__global__ __launch_bounds__(256)
void ln_rows(const void* __restrict__ In, void* __restrict__ Out,
             const float* __restrict__ g, const float* __restrict__ bb)
{
  const int row = blockIdx.x;
  const int tid = threadIdx.x;
  const size_t base = (size_t)row*1024 + tid*4;
  float v[4];
  if constexpr (INF32){
    f32x4 t = *reinterpret_cast<const f32x4*>((const float*)In + base);
    v[0]=t[0]; v[1]=t[1]; v[2]=t[2]; v[3]=t[3];
  } else {
    u16x4 t = *reinterpret_cast<const u16x4*>((const unsigned short*)In + base);
    #pragma unroll
    for (int j=0;j<4;j++) v[j] = b2f(t[j]);
  }
  float s = v[0]+v[1]+v[2]+v[3];
  float q = v[0]*v[0]+v[1]*v[1]+v[2]*v[2]+v[3]*v[3];
  #pragma unroll
  for (int o=32;o>0;o>>=1){ s += __shfl_xor(s,o,64); q += __shfl_xor(q,o,64); }
  __shared__ float sm[8];
  const int wave = tid>>6, lane = tid&63;
  if (lane==0){ sm[wave] = s; sm[4+wave] = q; }
  __syncthreads();
  s = sm[0]+sm[1]+sm[2]+sm[3];
  q = sm[4]+sm[5]+sm[6]+sm[7];
  const float mean = s*(1.f/1024.f);
  const float rstd = rsqrtf(fmaxf(q*(1.f/1024.f) - mean*mean, 0.f) + 1e-5f);
  #pragma unroll
  for (int j=0;j<4;j++){
    float t2 = (v[j]-mean)*rstd;
    if constexpr (HASGB) t2 = t2*g[tid*4+j] + bb[tid*4+j];
    v[j] = t2;
  }
  if constexpr (OUTF32){
    f32x4 t{v[0],v[1],v[2],v[3]};
    *reinterpret_cast<f32x4*>((float*)Out + base) = t;
  } else {
    u16x4 t{f2b(v[0]),f2b(v[1]),f2b(v[2]),f2b(v[3])};
    *reinterpret_cast<u16x4*>((unsigned short*)Out + base) = t;
  }
}

// ---------------------------------------------------------------- misc
template<bool LO>
__global__ __launch_bounds__(256)
void transpose_cvt(const float* __restrict__ W, const float* __restrict__ rs,
                   unsigned short* __restrict__ Wt, unsigned short* __restrict__ Wtlo,
                   int K, int N)
{
  __shared__ float t[32][33];
  const int tx = threadIdx.x & 31, ty = threadIdx.x >> 5;
  const int n0 = blockIdx.x*32, k0 = blockIdx.y*32;
  #pragma unroll
  for (int j=0;j<4;j++){
    int r = ty + j*8;
    float w = W[(size_t)(k0+r)*N + n0 + tx];
    if (rs) w *= rs[k0+r];
    t[r][tx] = w;
  }
  __syncthreads();
  #pragma unroll
  for (int j=0;j<4;j++){
    int r = ty + j*8;
    float w = t[tx][r];
    unsigned short hi = f2b(w);
    Wt[(size_t)(n0+r)*K + k0 + tx] = hi;
    if constexpr (LO)
      Wtlo[(size_t)(n0+r)*K + k0 + tx] = f2b(w - b2f(hi));
  }
}

__global__ __launch_bounds__(256)
void biaskv_kernel(const float* __restrict__ ln1b, const float* __restrict__ wkv,
                   float* __restrict__ out)
{
  const int l = blockIdx.y;
  const int n = blockIdx.x*256 + threadIdx.x;
  const float* b1 = ln1b + l*1024;
  const float* W  = wkv + (size_t)l*1024*2048;
  float s = 0.f;
  for (int k=0;k<1024;k++) s += b1[k]*W[(size_t)k*2048 + n];
  out[l*2048 + n] = s;
}

__global__ __launch_bounds__(256)
void init_latents(const float* __restrict__ Q, float* __restrict__ L)
{
  size_t idx = ((size_t)blockIdx.x*256 + threadIdx.x)*4;
  int row = (int)(idx >> 10);
  int col = (int)(idx & 1023);
  f32x4 t = *reinterpret_cast<const f32x4*>(Q + (size_t)(row & 15)*1024 + col);
  *reinterpret_cast<f32x4*>(L + idx) = t;
}

// ---------------------------------------------------------------- attention (unchanged from R3)
__global__ __launch_bounds__(256)
void attn_kernel(const float* __restrict__ QLTf,
                 const unsigned short* __restrict__ KVX,
                 const float* __restrict__ KVLTf,
                 float* __restrict__ ATTOf)
{
  __shared__ float qs[16][64];
  __shared__ float ws[16][600];
  const int tid = threadIdx.x;
  const int bh = blockIdx.x;
  const int b = bh >> 4, h = bh & 15;

  {
    int idx = tid*4;
    int qi = idx >> 6, d = idx & 63;
    f32x4 t = *reinterpret_cast<const f32x4*>(QLTf + (size_t)(b*16+qi)*1024 + h*64 + d);
    #pragma unroll
    for (int j=0;j<4;j++) qs[qi][d+j] = 0.125f * t[j];
  }
  __syncthreads();

  for (int r = tid; r < 593; r += 256){
    float a[16];
    #pragma unroll
    for (int qi=0;qi<16;qi++) a[qi] = 0.f;
    if (r < 577){
      const unsigned short* krow = KVX + ((size_t)(b*577 + r)*2048 + h*64);
      #pragma unroll 4
      for (int d4=0; d4<16; d4++){
        u16x4 k4 = *reinterpret_cast<const u16x4*>(krow + d4*4);
        float kf0=b2f(k4[0]), kf1=b2f(k4[1]), kf2=b2f(k4[2]), kf3=b2f(k4[3]);
        #pragma unroll
        for (int qi=0;qi<16;qi++){
          f32x4 q4 = *reinterpret_cast<const f32x4*>(&qs[qi][d4*4]);
          a[qi] += q4[0]*kf0 + q4[1]*kf1 + q4[2]*kf2 + q4[3]*kf3;
        }
      }
    } else {
      const float* krow = KVLTf + ((size_t)(b*16 + (r-577))*2048 + h*64);
      #pragma unroll 4
      for (int d4=0; d4<16; d4++){
        f32x4 k4 = *reinterpret_cast<const f32x4*>(krow + d4*4);
        #pragma unroll
        for (int qi=0;qi<16;qi++){
          f32x4 q4 = *reinterpret_cast<const f32x4*>(&qs[qi][d4*4]);
          a[qi] += q4[0]*k4[0] + q4[1]*k4[1] + q4[2]*k4[2] + q4[3]*k4[3];
        }
      }
    }
    #pragma unroll
    for (int qi=0;qi<16;qi++) ws[qi][r] = a[qi];
  }
  __syncthreads();

  const int wave = tid>>6, lane = tid&63;
  for (int qi = wave; qi < 16; qi += 4){
    float m = -1e30f;
    for (int r = lane; r < 593; r += 64) m = fmaxf(m, ws[qi][r]);
    #pragma unroll
    for (int o=32;o>0;o>>=1) m = fmaxf(m, __shfl_xor(m,o,64));
    float s = 0.f;
    for (int r = lane; r < 593; r += 64){ float e = expf(ws[qi][r]-m); ws[qi][r] = e; s += e; }
    #pragma unroll
    for (int o=32;o>0;o>>=1) s += __shfl_xor(s,o,64);
    float inv = 1.f/s;
    for (int r = lane; r < 593; r += 64) ws[qi][r] *= inv;
  }
  __syncthreads();

  const int d = tid & 63, qg = tid >> 6;
  float o0=0.f,o1=0.f,o2=0.f,o3=0.f;
  for (int rr=0; rr<576; rr+=4){
    f32x4 w0 = *reinterpret_cast<const f32x4*>(&ws[qg   ][rr]);
    f32x4 w1 = *reinterpret_cast<const f32x4*>(&ws[qg+4 ][rr]);
    f32x4 w2 = *reinterpret_cast<const f32x4*>(&ws[qg+8 ][rr]);
    f32x4 w3 = *reinterpret_cast<const f32x4*>(&ws[qg+12][rr]);
    #pragma unroll
    for (int j=0;j<4;j++){
      const unsigned short* vrow = KVX + ((size_t)(b*577 + rr + j)*2048 + 1024 + h*64);
      float v = b2f(vrow[d]);
      o0 += w0[j]*v; o1 += w1[j]*v; o2 += w2[j]*v; o3 += w3[j]*v;
    }
  }
  {
    float v = b2f(KVX[(size_t)(b*577 + 576)*2048 + 1024 + h*64 + d]);
    o0 += ws[qg][576]*v; o1 += ws[qg+4][576]*v; o2 += ws[qg+8][576]*v; o3 += ws[qg+12][576]*v;
  }
  for (int r=577; r<593; r++){
    float v = KVLTf[(size_t)(b*16 + (r-577))*2048 + 1024 + h*64 + d];
    o0 += ws[qg][r]*v; o1 += ws[qg+4][r]*v; o2 += ws[qg+8][r]*v; o3 += ws[qg+12][r]*v;
  }
  ATTOf[(size_t)(b*16+qg   )*1024 + h*64 + d] = o0;
  ATTOf[(size_t)(b*16+qg+4 )*1024 + h*64 + d] = o1;
  ATTOf[(size_t)(b*16+qg+8 )*1024 + h*64 + d] = o2;
  ATTOf[(size_t)(b*16+qg+12)*1024 + h*64 + d] = o3;
}

// ---------------------------------------------------------------- host
extern "C" void kernel_launch(void* const* d_in, const int* in_sizes, int n_in,
                              void* d_out, int out_size, void* d_ws, size_t ws_size,
                              hipStream_t stream)
{
  const float* x    = (const float*)d_in[0];
  const float* qry  = (const float*)d_in[1];
  const float* piw  = (const float*)d_in[2];
  const float* pib  = (const float*)d_in[3];
  const float* ln1g = (const float*)d_in[4];
  const float* ln1b = (const float*)d_in[5];
  const float* ln2g = (const float*)d_in[6];
  const float* ln2b = (const float*)d_in[7];
  const float* wq   = (const float*)d_in[8];
  const float* wkv  = (const float*)d_in[9];
  const float* wo   = (const float*)d_in[10];
  const float* ffg  = (const float*)d_in[11];
  const float* ffb  = (const float*)d_in[12];
  const float* w1   = (const float*)d_in[13];
  const float* w2   = (const float*)d_in[14];
  const float* pow_ = (const float*)d_in[15];
  const float* pob  = (const float*)d_in[16];
  const float* ng   = (const float*)d_in[17];
  const float* nb   = (const float*)d_in[18];

  const int MROWS = 64*577;     // 36928
  char* wsb = (char*)d_ws;
  size_t off = 0;
  auto alloc = [&](size_t bytes)->char*{
    char* p = wsb + off; off = (off + bytes + 255) & ~(size_t)255; return p;
  };
  unsigned short* XP    = (unsigned short*)alloc((size_t)36992*1024*2);
  unsigned short* KVX   = (unsigned short*)alloc((size_t)36992*2048*2);
  unsigned short* WpiT  = (unsigned short*)alloc((size_t)1024*768*2);
  unsigned short* WkvTs = (unsigned short*)alloc((size_t)2048*1024*2);
  unsigned short* WkvT  = (unsigned short*)alloc((size_t)2048*1024*2);
  unsigned short* WkvTl = (unsigned short*)alloc((size_t)2048*1024*2);
  unsigned short* WqT   = (unsigned short*)alloc((size_t)1024*1024*2);
  unsigned short* WqTl  = (unsigned short*)alloc((size_t)1024*1024*2);
  unsigned short* WoT   = (unsigned short*)alloc((size_t)1024*1024*2);
  unsigned short* WoTl  = (unsigned short*)alloc((size_t)1024*1024*2);
  unsigned short* W1T   = (unsigned short*)alloc((size_t)4096*1024*2);
  unsigned short* W1Tl  = (unsigned short*)alloc((size_t)4096*1024*2);
  unsigned short* W2T   = (unsigned short*)alloc((size_t)1024*4096*2);
  unsigned short* W2Tl  = (unsigned short*)alloc((size_t)1024*4096*2);
  float*          BKV   = (float*)alloc((size_t)8*2048*4);
  float*          LTf   = (float*)alloc((size_t)1024*1024*4);   // also FFIN
  float*          QLTf  = (float*)alloc((size_t)1024*1024*4);
  float*          KVLTf = (float*)alloc((size_t)1024*2048*4);
  float*          ATTOf = (float*)alloc((size_t)1024*1024*4);   // also OUTP after loop
  float*          FFHf  = (float*)alloc((size_t)1024*4096*4);
  float*          LATF  = (float*)alloc((size_t)1024*1024*4);
  if (off > ws_size) return;  // loud failure (output stays zero)

  dim3 blk(256);

  // ---- prep
  transpose_cvt<false><<<dim3(32,24), blk, 0, stream>>>(piw, nullptr, WpiT, nullptr, 768, 1024);
  biaskv_kernel<<<dim3(8,8),   blk, 0, stream>>>(ln1b, wkv, BKV);
  init_latents<<<dim3(1024),   blk, 0, stream>>>(qry, LATF);

  // xp = x @ proj_in_w + b  (bf16 MFMA), then LN in place -> xhat (bf16)
  gemm_bt<128,128,true><<<dim3(8,289), blk, 0, stream>>>(
      x, WpiT, pib, XP, MROWS, 1024, 768);
  ln_rows<false,false,false><<<dim3(MROWS), blk, 0, stream>>>(XP, XP, nullptr, nullptr);

  for (int l=0; l<8; l++){
    transpose_cvt<false><<<dim3(64,32),  blk, 0, stream>>>(wkv + (size_t)l*1024*2048, ln1g + l*1024, WkvTs, nullptr, 1024, 2048);
    transpose_cvt<true ><<<dim3(64,32),  blk, 0, stream>>>(wkv + (size_t)l*1024*2048, nullptr, WkvT, WkvTl, 1024, 2048);
    transpose_cvt<true ><<<dim3(32,32),  blk, 0, stream>>>(wq  + (size_t)l*1024*1024, nullptr, WqT,  WqTl, 1024, 1024);
    transpose_cvt<true ><<<dim3(32,32),  blk, 0, stream>>>(wo  + (size_t)l*1024*1024, nullptr, WoT,  WoTl, 1024, 1024);
    transpose_cvt<true ><<<dim3(128,32), blk, 0, stream>>>(w1  + (size_t)l*1024*4096, nullptr, W1T,  W1Tl, 1024, 4096);
    transpose_cvt<true ><<<dim3(32,128), blk, 0, stream>>>(w2  + (size_t)l*4096*1024, nullptr, W2T,  W2Tl, 4096, 1024);

    // lt = LN(latents, g2,b2)  (fp32)
    ln_rows<true,true,true><<<dim3(1024), blk, 0, stream>>>(LATF, LTf, ln2g + l*1024, ln2b + l*1024);
    // q_lt = lt @ Wq ; kv_lt = lt @ Wkv   (split MFMA, fp32-accurate)
    gemm_sp<EPI_F32><<<dim3(16,16), blk, 0, stream>>>(
        LTf, WqT, WqTl, nullptr, nullptr, QLTf, 1024, 1024, 1024);
    gemm_sp<EPI_F32><<<dim3(16,32), blk, 0, stream>>>(
        LTf, WkvT, WkvTl, nullptr, nullptr, KVLTf, 1024, 2048, 1024);
    // kv_x = xhat @ (g1-scaled Wkv) + b1@Wkv   (bf16 MFMA, washout-protected)
    gemm_bt<128,128,false><<<dim3(16,289), blk, 0, stream>>>(
        XP, WkvTs, BKV + l*2048, KVX, MROWS, 2048, 1024);
    // attention (fp32 softmax; fp32 q and latent k/v)
    attn_kernel<<<dim3(1024), blk, 0, stream>>>(QLTf, KVX, KVLTf, ATTOf);
    // latents += o @ Wo  (split)
    gemm_sp<EPI_RESF32><<<dim3(16,16), blk, 0, stream>>>(
        ATTOf, WoT, WoTl, nullptr, LATF, LATF, 1024, 1024, 1024);
    // FF (split)
    ln_rows<true,true,true><<<dim3(1024), blk, 0, stream>>>(LATF, LTf, ffg + l*1024, ffb + l*1024);
    gemm_sp<EPI_GELU><<<dim3(16,64), blk, 0, stream>>>(
        LTf, W1T, W1Tl, nullptr, nullptr, FFHf, 1024, 4096, 1024);
    gemm_sp<EPI_RESF32><<<dim3(16,16), blk, 0, stream>>>(
        FFHf, W2T, W2Tl, nullptr, LATF, LATF, 1024, 1024, 4096);
  }

  // out = LN(latents @ Wpo + b, nout)  (split; reuse WqT buffers for Wpo)
  transpose_cvt<true><<<dim3(32,32), blk, 0, stream>>>(pow_, nullptr, WqT, WqTl, 1024, 1024);
  gemm_sp<EPI_F32><<<dim3(16,16), blk, 0, stream>>>(
      LATF, WqT, WqTl, pob, nullptr, ATTOf, 1024, 1024, 1024);
  ln_rows<true,true,true><<<dim3(1024), blk, 0, stream>>>(ATTOf, d_out, ng, nb);
}